// Round 11
// baseline (1666.315 us; speedup 1.0000x reference)
//
#include <hip/hip_runtime.h>
#include <stdint.h>
#include <math.h>

#define BB 8
#define NN 16384
#define CC 13
#define GG 512
#define KK 32

#define NEIGH_ELEMS (BB*GG*KK*CC)   // 1,703,936

// ---------------------------------------------------------------------------
// Pack: x[B,N,13] (fp32) -> f32 SoA planes px,py,pz (channels 4..6).
// ---------------------------------------------------------------------------
__global__ void pack_kernel(const float* __restrict__ x,
                            float* __restrict__ px, float* __restrict__ py,
                            float* __restrict__ pz) {
    int i = blockIdx.x * blockDim.x + threadIdx.x;
    if (i >= BB * NN) return;
    const float* p = x + (size_t)i * CC + 4;
    px[i] = p[0]; py[i] = p[1]; pz[i] = p[2];
}

// ---------------------------------------------------------------------------
// FPS v6: one block (512 threads) per batch, 32 pts/thread, persistent state
// (X,Y,Z,MD = 128 floats/thread) held in the AGPR FILE via explicit
// v_accvgpr_read/write inline asm ("a" register constraints).
// R6/R8/R9/R10 post-mortem: the VGPR allocator caps this kernel at ~100 arch
// VGPRs regardless of __launch_bounds__ / waves_per_eu, spilling ~50 values
// to scratch (~2-3K cyc/step reload tax). AGPRs sidestep that: unified
// 512-reg/wave file, 1-op moves, arch-VGPR working set ~50.
// 'volatile' keeps the loop-invariant X/Y/Z reads inside the step loop.
// One parity barrier per step; center via scalar (readfirstlane) load.
// fp32 math verbatim from R6 (bit-exact vs golden).
// ---------------------------------------------------------------------------
__global__ __launch_bounds__(512)
__attribute__((amdgpu_waves_per_eu(2, 2)))
void fps_kernel(const float* __restrict__ px,
                const float* __restrict__ py,
                const float* __restrict__ pz,
                float* __restrict__ centers) {
    const int b = blockIdx.x;
    const int t = threadIdx.x;
    const float* PX = px + b * NN;
    const float* PY = py + b * NN;
    const float* PZ = pz + b * NN;

    // AGPR-resident state (only ever touched through accvgpr moves)
    float XA[32], YA[32], ZA[32], MDA[32];
#pragma unroll
    for (int i = 0; i < 32; ++i) {
        int pos = t + (i << 9);
        float vx = PX[pos], vy = PY[pos], vz = PZ[pos];
        float md0 = 1e10f;   // init_d = 10000000000.0
        asm volatile("v_accvgpr_write_b32 %0, %1" : "=a"(XA[i])  : "v"(vx));
        asm volatile("v_accvgpr_write_b32 %0, %1" : "=a"(YA[i])  : "v"(vy));
        asm volatile("v_accvgpr_write_b32 %0, %1" : "=a"(ZA[i])  : "v"(vz));
        asm volatile("v_accvgpr_write_b32 %0, %1" : "=a"(MDA[i]) : "v"(md0));
    }

    __shared__ float s_v[2][8];
    __shared__ int   s_p[2][8];

    int wp = 0;   // current center index (uniform across block)
    if (t == 0) {
        float* oc = centers + (size_t)b * GG * 3;
        oc[0] = PX[0]; oc[1] = PY[0]; oc[2] = PZ[0];
    }

    for (int g = 1; g < GG; ++g) {
        // scalar broadcast load of current center coords (uniform index)
        int swp = __builtin_amdgcn_readfirstlane(wp);
        float lx = PX[swp], ly = PY[swp], lz = PZ[swp];
        float bv = -1.0f;
        int bp = 0x7fffffff;
#pragma unroll
        for (int i = 0; i < 32; ++i) {
            float xi, yi, zi, mdi;
            asm volatile("v_accvgpr_read_b32 %0, %1" : "=v"(xi)  : "a"(XA[i]));
            asm volatile("v_accvgpr_read_b32 %0, %1" : "=v"(yi)  : "a"(YA[i]));
            asm volatile("v_accvgpr_read_b32 %0, %1" : "=v"(zi)  : "a"(ZA[i]));
            asm volatile("v_accvgpr_read_b32 %0, %1" : "=v"(mdi) : "a"(MDA[i]));
            float e0 = __fsub_rn(xi, lx);
            float e1 = __fsub_rn(yi, ly);
            float e2 = __fsub_rn(zi, lz);
            float d  = __fadd_rn(__fadd_rn(__fmul_rn(e0, e0), __fmul_rn(e1, e1)),
                                 __fmul_rn(e2, e2));
            float m = fminf(mdi, d);   // np.minimum
            asm volatile("v_accvgpr_write_b32 %0, %1" : "=a"(MDA[i]) : "v"(m));
            // ascending-index scan + strict '>' keeps lowest index on ties
            if (m > bv) { bv = m; bp = t + (i << 9); }
        }
        // wave(64) butterfly argmax, tie -> lower flat index
#pragma unroll
        for (int off = 32; off >= 1; off >>= 1) {
            float ov = __shfl_xor(bv, off);
            int   op = __shfl_xor(bp, off);
            if (ov > bv || (ov == bv && op < bp)) { bv = ov; bp = op; }
        }
        int par = g & 1;
        int w = t >> 6;
        if ((t & 63) == 0) { s_v[par][w] = bv; s_p[par][w] = bp; }
        __syncthreads();
        // redundant scan of 8 partials by every thread (LDS broadcast reads)
        float wv = s_v[par][0]; int wi = s_p[par][0];
#pragma unroll
        for (int q = 1; q < 8; ++q) {
            float qv = s_v[par][q]; int qp = s_p[par][q];
            if (qv > wv || (qv == wv && qp < wi)) { wv = qv; wi = qp; }
        }
        wp = wi;
        if (t == 0) {
            float* oc = centers + ((size_t)b * GG + g) * 3;
            oc[0] = PX[wp]; oc[1] = PY[wp]; oc[2] = PZ[wp];
        }
        // no second barrier: parity buffer isolates next round's writes
    }
}

// ---------------------------------------------------------------------------
// KNN v2 + gather (unchanged from R8): one 256-thread block per center,
// 64 pts/thread, top-2 cache + rare global rescan; XCD swizzle keeps each
// batch's SoA L2-resident on one XCD. d2 math bit-exact vs golden.
// ---------------------------------------------------------------------------
__global__ __launch_bounds__(256, 8) void knn_kernel(const float* __restrict__ px,
                                                     const float* __restrict__ py,
                                                     const float* __restrict__ pz,
                                                     const float* __restrict__ x,
                                                     const float* __restrict__ centers,
                                                     float* __restrict__ out) {
    const int blk = blockIdx.x;
    const int bg  = ((blk & 7) << 9) | (blk >> 3);   // batch = blk&7 -> one XCD
    const int b   = bg >> 9;
    const int t   = threadIdx.x;

    const float* ctr = centers + (size_t)bg * 3;
    float cx = ctr[0], cy = ctr[1], cz = ctr[2];
    float cc2 = __fadd_rn(__fadd_rn(__fmul_rn(cx, cx), __fmul_rn(cy, cy)),
                          __fmul_rn(cz, cz));

    const float* PX = px + b * NN;
    const float* PY = py + b * NN;
    const float* PZ = pz + b * NN;

    float k1 = INFINITY, k2 = INFINITY;
    int   p1 = 0x7fffffff, p2 = 0x7fffffff;
    uint64_t mask = 0;   // consumed elements of my 64-pt chunk

#pragma unroll 4
    for (int i = 0; i < 64; ++i) {
        int pos = (i << 8) + t;           // coalesced
        float ax = PX[pos], ay = PY[pos], az = PZ[pos];
        float pp2 = __fadd_rn(__fadd_rn(__fmul_rn(ax, ax), __fmul_rn(ay, ay)),
                              __fmul_rn(az, az));
        float dot = fmaf(cz, az, fmaf(cy, ay, __fmul_rn(cx, ax)));
        float d2  = __fsub_rn(__fadd_rn(cc2, pp2), __fmul_rn(2.0f, dot));
        // ascending pos scan, strict '<': ties keep lower pos
        if (d2 < k1)      { k2 = k1; p2 = p1; k1 = d2; p1 = pos; }
        else if (d2 < k2) { k2 = d2; p2 = pos; }
    }

    __shared__ float s_v[2][4];
    __shared__ int   s_p[2][4];
    __shared__ int   s_chosen[KK];

    for (int j = 0; j < KK; ++j) {
        float v = k1; int vp = p1;
#pragma unroll
        for (int off = 32; off >= 1; off >>= 1) {
            float ov = __shfl_xor(v, off);
            int   op = __shfl_xor(vp, off);
            if (ov < v || (ov == v && op < vp)) { v = ov; vp = op; }
        }
        int par = j & 1;
        int w = t >> 6;
        if ((t & 63) == 0) { s_v[par][w] = v; s_p[par][w] = vp; }
        __syncthreads();
        // redundant scan of 4 partials by every thread
        float wv = s_v[par][0]; int wp = s_p[par][0];
#pragma unroll
        for (int q = 1; q < 4; ++q) {
            float qv = s_v[par][q]; int qp = s_p[par][q];
            if (qv < wv || (qv == wv && qp < wp)) { wv = qv; wp = qp; }
        }
        if (t == 0) s_chosen[j] = wp;
        if ((wp & 255) == t) {
            // I owned the extracted point: mark consumed, promote second
            mask |= 1ull << (wp >> 8);
            k1 = k2; p1 = p2;
            k2 = INFINITY; p2 = 0x7fffffff;
            if (p1 == 0x7fffffff && mask != 0xffffffffffffffffull) {
                // top-2 exhausted (rare): rebuild from unmasked points,
                // reloading coords from global; d2 bit-identical
                k1 = INFINITY;
#pragma unroll 1
                for (int i = 0; i < 64; ++i) {
                    if ((mask >> i) & 1ull) continue;
                    int pos = (i << 8) + t;
                    float ax = PX[pos], ay = PY[pos], az = PZ[pos];
                    float pp2 = __fadd_rn(__fadd_rn(__fmul_rn(ax, ax), __fmul_rn(ay, ay)),
                                          __fmul_rn(az, az));
                    float dot = fmaf(cz, az, fmaf(cy, ay, __fmul_rn(cx, ax)));
                    float d2  = __fsub_rn(__fadd_rn(cc2, pp2), __fmul_rn(2.0f, dot));
                    if (d2 < k1)      { k2 = k1; p2 = p1; k1 = d2; p1 = pos; }
                    else if (d2 < k2) { k2 = d2; p2 = pos; }
                }
            }
        }
        // no second barrier: parity buffer isolates next round's writes
    }
    __syncthreads();   // s_chosen visibility for gather

    // gather: 32 neighbors x 13 channels; subtract center from ch 4..6
    for (int v = t; v < KK * CC; v += 256) {
        int j = v / CC, c = v - j * CC;
        int pt = s_chosen[j] & (NN - 1);   // safety clamp (no-op when correct)
        float val = x[((size_t)b * NN + pt) * CC + c];
        if (c >= 4 && c < 7) {
            float cs = (c == 4) ? cx : ((c == 5) ? cy : cz);
            val = __fsub_rn(val, cs);
        }
        out[((size_t)bg * KK + j) * CC + c] = val;
    }
}

extern "C" void kernel_launch(void* const* d_in, const int* in_sizes, int n_in,
                              void* d_out, int out_size, void* d_ws, size_t ws_size,
                              hipStream_t stream) {
    const float* x = (const float*)d_in[0];
    float* out = (float*)d_out;
    float* centers = out + NEIGH_ELEMS;   // output 1 follows output 0, flat

    float* px = (float*)d_ws;
    float* py = px + BB * NN;
    float* pz = py + BB * NN;

    pack_kernel<<<(BB * NN + 255) / 256, 256, 0, stream>>>(x, px, py, pz);
    fps_kernel<<<BB, 512, 0, stream>>>(px, py, pz, centers);
    knn_kernel<<<BB * GG, 256, 0, stream>>>(px, py, pz, x, centers, out);
}